// Round 2
// baseline (1089.876 us; speedup 1.0000x reference)
//
#include <hip/hip_runtime.h>
#include <hip/hip_bf16.h>
#include <math.h>

typedef __bf16 bf16x8 __attribute__((ext_vector_type(8)));
typedef float  f32x4  __attribute__((ext_vector_type(4)));
typedef float  f32x16 __attribute__((ext_vector_type(16)));

#define MFMA16(a, b, c) __builtin_amdgcn_mfma_f32_16x16x32_bf16((a), (b), (c), 0, 0, 0)
#define MFMA32(a, b, c) __builtin_amdgcn_mfma_f32_32x32x16_bf16((a), (b), (c), 0, 0, 0)

static constexpr int    kB  = 16;
static constexpr int    kS  = 2048;
static constexpr int    kC  = 512;
static constexpr size_t kNE = (size_t)kB * kS * kC;  // 16777216

static __device__ __forceinline__ void split_bf16(float v, __bf16 &hi, __bf16 &lo) {
  hi = (__bf16)v;                 // RNE
  lo = (__bf16)(v - (float)hi);   // residual, ~2^-17 combined rel error
}

// Byte offset into a [rows][64] bf16 tile (128 B rows), XOR-swizzled in 16 B chunks.
// Conflict-free for b128 ops where row varies per lane at a fixed column chunk.
static __device__ __forceinline__ int swzb(int row, int e) {
  return ((row << 7) + (e << 1)) ^ ((row & 7) << 4);
}
// Byte offset into a [rows][128] bf16 tile (256 B rows), XOR-swizzled.
static __device__ __forceinline__ int swzp(int row, int e) {
  return ((row << 8) + (e << 1)) ^ ((row & 7) << 4);
}

// Split 16 staged fp32 into bf16 hi/lo and store to swizzled LDS tiles.
static __device__ __forceinline__ void split_store16_swz(
    float4 v0, float4 v1, float4 v2, float4 v3, char* hi, char* lo, int row, int e0) {
  float vv[16] = {v0.x, v0.y, v0.z, v0.w, v1.x, v1.y, v1.z, v1.w,
                  v2.x, v2.y, v2.z, v2.w, v3.x, v3.y, v3.z, v3.w};
  bf16x8 h0, h1, l0, l1;
#pragma unroll
  for (int i = 0; i < 8; ++i) {
    __bf16 a, b;
    split_bf16(vv[i], a, b);     h0[i] = a; l0[i] = b;
    split_bf16(vv[8 + i], a, b); h1[i] = a; l1[i] = b;
  }
  *(bf16x8*)(hi + swzb(row, e0))     = h0;
  *(bf16x8*)(hi + swzb(row, e0 + 8)) = h1;
  *(bf16x8*)(lo + swzb(row, e0))     = l0;
  *(bf16x8*)(lo + swzb(row, e0 + 8)) = l1;
}

// ---------------- K1a: t = tanh(x'), split to bf16 hi/lo ----------------
__global__ __launch_bounds__(256) void k_tanh_split(
    const float* __restrict__ xp, __bf16* __restrict__ th, __bf16* __restrict__ tl) {
  size_t i = ((size_t)blockIdx.x * 256 + threadIdx.x) * 8;
  float4 a = *(const float4*)(xp + i);
  float4 b = *(const float4*)(xp + i + 4);
  float v[8] = {a.x, a.y, a.z, a.w, b.x, b.y, b.z, b.w};
  bf16x8 h, l;
#pragma unroll
  for (int k = 0; k < 8; ++k) {
    float t = tanhf(v[k]);
    __bf16 hh, ll;
    split_bf16(t, hh, ll);
    h[k] = hh; l[k] = ll;
  }
  *(bf16x8*)(th + i) = h;
  *(bf16x8*)(tl + i) = l;
}

// ---------------- K1c: x (fp32 [b][t][c]) -> bf16 transposed [b][c][t] ----------------
__global__ __launch_bounds__(256) void k_transpose_x(
    const float* __restrict__ x, __bf16* __restrict__ xbt) {
  __shared__ float tile[64][65];
  int bid = blockIdx.x;              // 16 * 32 * 8 = 4096
  int b   = bid >> 8;
  int t0  = ((bid >> 3) & 31) * 64;
  int c0  = (bid & 7) * 64;
  int row = threadIdx.x >> 2;        // 0..63
  int seg = threadIdx.x & 3;         // 0..3 (16 elems each)
  const float* src = x + (size_t)(b * kS + t0 + row) * kC + c0 + seg * 16;
  float4 v0 = *(const float4*)(src + 0);
  float4 v1 = *(const float4*)(src + 4);
  float4 v2 = *(const float4*)(src + 8);
  float4 v3 = *(const float4*)(src + 12);
  float vv[16] = {v0.x, v0.y, v0.z, v0.w, v1.x, v1.y, v1.z, v1.w,
                  v2.x, v2.y, v2.z, v2.w, v3.x, v3.y, v3.z, v3.w};
#pragma unroll
  for (int i = 0; i < 16; ++i) tile[row][seg * 16 + i] = vv[i];
  __syncthreads();
  bf16x8 o0, o1;
#pragma unroll
  for (int i = 0; i < 8; ++i) o0[i] = (__bf16)tile[seg * 16 + i][row];
#pragma unroll
  for (int i = 0; i < 8; ++i) o1[i] = (__bf16)tile[seg * 16 + 8 + i][row];
  __bf16* dst = xbt + (size_t)(b * kC + c0 + row) * kS + t0 + seg * 16;
  *(bf16x8*)(dst)     = o0;
  *(bf16x8*)(dst + 8) = o1;
}

// ---------------- K1b: q = x' @ W^T + bias, fp32-accurate via split-bf16 3-MFMA ----------------
__global__ __launch_bounds__(256) void k_qgemm(
    const float* __restrict__ xp, const float* __restrict__ W,
    const float* __restrict__ bias, __bf16* __restrict__ qh, __bf16* __restrict__ ql) {
  __shared__ __align__(16) char lds[32768];
  char* Ah = lds;             // [64][64] swizzled
  char* Al = lds + 8192;
  char* Bh = lds + 16384;     // [64][64] swizzled (W rows d, cols c)
  char* Bl = lds + 24576;

  int bid = blockIdx.x;         // 512 m-tiles * 8 n-tiles
  int n0  = (bid & 7) * 64;
  int m0  = (bid >> 3) * 64;

  int tid  = threadIdx.x;
  int lane = tid & 63;
  int wave = tid >> 6;
  int qd   = lane >> 4;
  int cl   = lane & 15;
  int row  = tid >> 2;
  int seg  = tid & 3;

  f32x4 acc[4] = {};
  const float* srcA = xp + (size_t)(m0 + row) * kC + seg * 16;
  const float* srcB = W  + (size_t)(n0 + row) * kC + seg * 16;

  float4 va0, va1, va2, va3, vb0, vb1, vb2, vb3;
  auto load_ab = [&](int kc) {
    const float* a = srcA + kc * 64;
    va0 = *(const float4*)(a);      va1 = *(const float4*)(a + 4);
    va2 = *(const float4*)(a + 8);  va3 = *(const float4*)(a + 12);
    const float* bb = srcB + kc * 64;
    vb0 = *(const float4*)(bb);     vb1 = *(const float4*)(bb + 4);
    vb2 = *(const float4*)(bb + 8); vb3 = *(const float4*)(bb + 12);
  };

  load_ab(0);
  for (int kc = 0; kc < 8; ++kc) {
    split_store16_swz(va0, va1, va2, va3, Ah, Al, row, seg * 16);
    split_store16_swz(vb0, vb1, vb2, vb3, Bh, Bl, row, seg * 16);
    __syncthreads();
    if (kc < 7) load_ab(kc + 1);   // fly next tile's loads under the MFMAs
    __builtin_amdgcn_s_setprio(1);
#pragma unroll
    for (int ks = 0; ks < 2; ++ks) {
      int ka = ks * 32 + qd * 8;
      bf16x8 ah = *(const bf16x8*)(Ah + swzb(wave * 16 + cl, ka));
      bf16x8 al = *(const bf16x8*)(Al + swzb(wave * 16 + cl, ka));
#pragma unroll
      for (int j = 0; j < 4; ++j) {
        bf16x8 bh = *(const bf16x8*)(Bh + swzb(j * 16 + cl, ka));
        bf16x8 bl = *(const bf16x8*)(Bl + swzb(j * 16 + cl, ka));
        acc[j] = MFMA16(ah, bh, acc[j]);
        acc[j] = MFMA16(ah, bl, acc[j]);
        acc[j] = MFMA16(al, bh, acc[j]);
      }
    }
    __builtin_amdgcn_s_setprio(0);
    __syncthreads();
  }
#pragma unroll
  for (int j = 0; j < 4; ++j) {
    int d = n0 + j * 16 + cl;
    float bv = bias[d];
#pragma unroll
    for (int r = 0; r < 4; ++r) {
      int m = m0 + wave * 16 + qd * 4 + r;
      float v = acc[j][r] + bv;
      __bf16 h, l;
      split_bf16(v, h, l);
      qh[(size_t)m * kC + d] = h;
      ql[(size_t)m * kC + d] = l;
    }
  }
}

// ---------------- K2: fused flash attention ----------------
// score (16x16x32, fp32-accurate 3-MFMA split) -> online softmax (wave-local)
// -> P to LDS -> PV with 32x32x16 MFMA (waves retiled 2x2; alpha/l broadcast
// through a 64-float LDS array). All LDS tiles XOR-swizzled; staging inline
// (short live ranges -> no spills).
__global__ __launch_bounds__(256, 2) void k_attn(
    const __bf16* __restrict__ th, const __bf16* __restrict__ tl,
    const __bf16* __restrict__ qh, const __bf16* __restrict__ ql,
    const __bf16* __restrict__ xbt, float* __restrict__ out) {
  __shared__ __align__(16) char lds[49664];
  char* Ah  = lds;             // [64][64]  swz   (8 KiB)
  char* Al  = lds + 8192;
  char* Bh  = lds + 16384;     // [128][64] swz   (16 KiB)
  char* Bl  = lds + 32768;
  char* P   = lds;             // [64][128] swzp, aliases Ah+Al (phase-disjoint)
  char* Xt0 = lds + 16384;     // [64][128] swzp, aliases Bh
  char* Xt1 = lds + 32768;     // [64][128] swzp, aliases Bl
  float* stat = (float*)(lds + 49152);  // 64 f32: per-row alpha (per tt) / l (epilogue)

  int bid = blockIdx.x;                       // 512
  int b   = (bid & 7) | ((bid >> 8) << 3);    // XCD-swizzle: same batch -> same XCD slot
  int s0  = ((bid >> 3) & 31) * 64;

  int tid  = threadIdx.x;
  int lane = tid & 63;
  int wave = tid >> 6;
  int qd   = lane >> 4;       // score-phase ids (16x16 layout)
  int cl   = lane & 15;
  int l31  = lane & 31;       // PV-phase ids (32x32 layout)
  int lh   = lane >> 5;
  int whalf = wave & 1;       // PV: row half (32 rows)
  int wcol  = wave >> 1;      // PV: col half (256 cols)

  const float LOG2E = 1.4426950408889634f;

  float m_r[4], l_r[4];
  f32x16 O[8] = {};   // tile t = step*2+nloc: rows whalf*32+rl, cols wcol*256+step*64+nloc*32+l31
#pragma unroll
  for (int r = 0; r < 4; ++r) { m_r[r] = -INFINITY; l_r[r] = 0.f; }

  const size_t rowbase = (size_t)b * kS;

  const int arow = tid >> 2, aseg = tid & 3;   // A stage: 64 rows x 4 segs of 16
  const int brow = tid >> 1, bseg = tid & 1;   // B stage: 128 rows x 2 segs of 32
  const int xrow = tid >> 2, xseg = tid & 3;   // Xt stage: 64 rows x 4 segs of 32
  const int prow = whalf * 32 + l31;           // PV A-fragment row

  for (int tt = 0; tt < 16; ++tt) {
    int t0 = tt * 128;
    f32x4 Sacc[8] = {};
    // ----- score phase: S[64 x 128] = T . Q^T over K=512 (16x16x32) -----
    for (int kc = 0; kc < 8; ++kc) {
      { // stage A: 64 rows x 64 k (hi+lo)
        size_t g = (rowbase + s0 + arow) * kC + kc * 64 + aseg * 16;
        bf16x8 h0 = *(const bf16x8*)(th + g), h1 = *(const bf16x8*)(th + g + 8);
        bf16x8 l0 = *(const bf16x8*)(tl + g), l1 = *(const bf16x8*)(tl + g + 8);
        *(bf16x8*)(Ah + swzb(arow, aseg * 16))     = h0;
        *(bf16x8*)(Ah + swzb(arow, aseg * 16 + 8)) = h1;
        *(bf16x8*)(Al + swzb(arow, aseg * 16))     = l0;
        *(bf16x8*)(Al + swzb(arow, aseg * 16 + 8)) = l1;
      }
      { // stage B: 128 q-rows x 64 k (hi+lo)
        size_t g = (rowbase + t0 + brow) * kC + kc * 64 + bseg * 32;
#pragma unroll
        for (int u = 0; u < 4; ++u) {
          bf16x8 vh = *(const bf16x8*)(qh + g + u * 8);
          bf16x8 vl = *(const bf16x8*)(ql + g + u * 8);
          *(bf16x8*)(Bh + swzb(brow, bseg * 32 + u * 8)) = vh;
          *(bf16x8*)(Bl + swzb(brow, bseg * 32 + u * 8)) = vl;
        }
      }
      __syncthreads();
      __builtin_amdgcn_s_setprio(1);
#pragma unroll
      for (int ks = 0; ks < 2; ++ks) {
        int ka = ks * 32 + qd * 8;
        bf16x8 ah = *(const bf16x8*)(Ah + swzb(wave * 16 + cl, ka));
        bf16x8 al = *(const bf16x8*)(Al + swzb(wave * 16 + cl, ka));
#pragma unroll
        for (int j = 0; j < 8; ++j) {
          bf16x8 bh = *(const bf16x8*)(Bh + swzb(j * 16 + cl, ka));
          bf16x8 bl = *(const bf16x8*)(Bl + swzb(j * 16 + cl, ka));
          Sacc[j] = MFMA16(ah, bh, Sacc[j]);
          Sacc[j] = MFMA16(ah, bl, Sacc[j]);
          Sacc[j] = MFMA16(al, bh, Sacc[j]);
        }
      }
      __builtin_amdgcn_s_setprio(0);
      __syncthreads();
    }
    // ----- online softmax (score layout: row = wave*16 + qd*4 + r) -----
    float rmax[4];
#pragma unroll
    for (int r = 0; r < 4; ++r) {
      float v = Sacc[0][r];
#pragma unroll
      for (int j = 1; j < 8; ++j) v = fmaxf(v, Sacc[j][r]);
      rmax[r] = v;
    }
#pragma unroll
    for (int mk = 1; mk < 16; mk <<= 1)
#pragma unroll
      for (int r = 0; r < 4; ++r)
        rmax[r] = fmaxf(rmax[r], __shfl_xor(rmax[r], mk, 64));
    float alpha[4], rsum[4];
#pragma unroll
    for (int r = 0; r < 4; ++r) {
      float mn = fmaxf(m_r[r], rmax[r]);
      alpha[r] = exp2f((m_r[r] - mn) * LOG2E);   // exp2(-inf)=0 on first tile
      m_r[r] = mn;
      rsum[r] = 0.f;
    }
#pragma unroll
    for (int j = 0; j < 8; ++j)
#pragma unroll
      for (int r = 0; r < 4; ++r) {
        float p = exp2f((Sacc[j][r] - m_r[r]) * LOG2E);
        Sacc[j][r] = p;
        rsum[r] += p;
      }
#pragma unroll
    for (int mk = 1; mk < 16; mk <<= 1)
#pragma unroll
      for (int r = 0; r < 4; ++r)
        rsum[r] += __shfl_xor(rsum[r], mk, 64);
#pragma unroll
    for (int r = 0; r < 4; ++r)
      l_r[r] = l_r[r] * alpha[r] + rsum[r];
    // broadcast alpha per row (PV retiles rows across waves)
    if (cl == 0) {
#pragma unroll
      for (int r = 0; r < 4; ++r) stat[wave * 16 + qd * 4 + r] = alpha[r];
    }
    // write P (C-layout -> A-layout via LDS); A region is dead here
#pragma unroll
    for (int j = 0; j < 8; ++j)
#pragma unroll
      for (int r = 0; r < 4; ++r) {
        int pr = wave * 16 + qd * 4 + r;
        *(__bf16*)(P + swzp(pr, j * 16 + cl)) = (__bf16)Sacc[j][r];
      }
    __syncthreads();
    // ----- PV phase: O[64 x 512] += P[64 x 128] . Xbt[128 x 512] (32x32x16) -----
    float ar[16];
#pragma unroll
    for (int i = 0; i < 16; ++i)
      ar[i] = stat[whalf * 32 + (i & 3) + 8 * (i >> 2) + 4 * lh];
    bf16x8 pa[8];
#pragma unroll
    for (int ks = 0; ks < 8; ++ks)
      pa[ks] = *(const bf16x8*)(P + swzp(prow, ks * 16 + lh * 8));
#pragma unroll
    for (int t = 0; t < 8; ++t)
#pragma unroll
      for (int i = 0; i < 16; ++i)
        O[t][i] *= ar[i];
#pragma unroll
    for (int step = 0; step < 4; ++step) {
      { // stage two 64-channel chunks: Xt0 (cols wcol=0) and Xt1 (cols wcol=1)
        size_t g0 = ((size_t)b * kC + step * 64 + xrow) * kS + t0 + xseg * 32;
        size_t g1 = g0 + (size_t)256 * kS;
#pragma unroll
        for (int u = 0; u < 4; ++u)
          *(bf16x8*)(Xt0 + swzp(xrow, xseg * 32 + u * 8)) = *(const bf16x8*)(xbt + g0 + u * 8);
#pragma unroll
        for (int u = 0; u < 4; ++u)
          *(bf16x8*)(Xt1 + swzp(xrow, xseg * 32 + u * 8)) = *(const bf16x8*)(xbt + g1 + u * 8);
      }
      __syncthreads();
      const char* Xt = wcol ? Xt1 : Xt0;
      __builtin_amdgcn_s_setprio(1);
#pragma unroll
      for (int ks = 0; ks < 8; ++ks) {
#pragma unroll
        for (int nloc = 0; nloc < 2; ++nloc) {
          bf16x8 xb = *(const bf16x8*)(Xt + swzp(nloc * 32 + l31, ks * 16 + lh * 8));
          O[step * 2 + nloc] = MFMA32(pa[ks], xb, O[step * 2 + nloc]);
        }
      }
      __builtin_amdgcn_s_setprio(0);
      __syncthreads();
    }
  }
  // ----- epilogue: out = tanh(O / l) -----
  if (cl == 0) {
#pragma unroll
    for (int r = 0; r < 4; ++r) stat[wave * 16 + qd * 4 + r] = l_r[r];
  }
  __syncthreads();
  float linv[16];
#pragma unroll
  for (int i = 0; i < 16; ++i)
    linv[i] = __builtin_amdgcn_rcpf(stat[whalf * 32 + (i & 3) + 8 * (i >> 2) + 4 * lh]);
#pragma unroll
  for (int t = 0; t < 8; ++t) {
    int colbase = wcol * 256 + (t >> 1) * 64 + (t & 1) * 32 + l31;
#pragma unroll
    for (int i = 0; i < 16; ++i) {
      int rowl = (i & 3) + 8 * (i >> 2) + 4 * lh;
      float v = O[t][i] * linv[i];
      float e = exp2f(2.f * LOG2E * v);          // e^{2v}; |v| <= ~6, no overflow
      out[(rowbase + s0 + whalf * 32 + rowl) * kC + colbase] =
          1.f - 2.f * __builtin_amdgcn_rcpf(e + 1.f);
    }
  }
}

extern "C" void kernel_launch(void* const* d_in, const int* in_sizes, int n_in,
                              void* d_out, int out_size, void* d_ws, size_t ws_size,
                              hipStream_t stream) {
  const float* x    = (const float*)d_in[0];
  const float* xp   = (const float*)d_in[1];
  const float* W    = (const float*)d_in[2];
  const float* bias = (const float*)d_in[3];
  float* out = (float*)d_out;

  // workspace layout (bf16): t_hi | t_lo | q_hi | q_lo | x_bt  -> 5 * 16.78M * 2B = 160 MiB
  __bf16* ws  = (__bf16*)d_ws;
  __bf16* th  = ws;
  __bf16* tl  = ws + kNE;
  __bf16* qh  = ws + 2 * kNE;
  __bf16* ql  = ws + 3 * kNE;
  __bf16* xbt = ws + 4 * kNE;

  k_tanh_split<<<8192, 256, 0, stream>>>(xp, th, tl);
  k_transpose_x<<<4096, 256, 0, stream>>>(x, xbt);
  k_qgemm<<<4096, 256, 0, stream>>>(xp, W, bias, qh, ql);
  k_attn<<<512, 256, 0, stream>>>(th, tl, qh, ql, xbt, out);
}